// Round 8
// baseline (1675.389 us; speedup 1.0000x reference)
//
#include <hip/hip_runtime.h>
#include <hip/hip_bf16.h>
#include <math.h>

#define H 128
#define RS 136   // LDS row stride in shorts (128 + 8 pad; keeps ds_read_b128 16B-aligned)
#define BSH 7    // bin shift: 128 nodes per bin
#define BINW 128
#define BCAP 3584  // max edges per bin the LDS sort handles (expected max ~2810)

typedef __attribute__((ext_vector_type(8))) short short8;
typedef __attribute__((ext_vector_type(4))) short short4v;
typedef __attribute__((ext_vector_type(4))) float f32x4;

// fp32 -> bf16 (RNE); values here are finite (no NaN handling needed)
__device__ __forceinline__ short f2bf(float f) {
    unsigned u = __float_as_uint(f);
    u += 0x7fff + ((u >> 16) & 1);
    return (short)(u >> 16);
}
__device__ __forceinline__ float bf2f(short h) {
    return __uint_as_float(((unsigned)(unsigned short)h) << 16);
}

// ---------------- CSR build ----------------
// Node space concatenated: [NP(isa) | NG(rel) | NP(rev)].

__global__ __launch_bounds__(256) void count_all_kernel(
    const int* __restrict__ e0, int E0, const int* __restrict__ e1, int E1,
    const int* __restrict__ e2, int E2, int* __restrict__ cnt, int NPn, int NGn) {
    int g = blockIdx.x * 256 + threadIdx.x;
    const int* ed; int E, lo, base;
    if (g < E0) { ed = e0; E = E0; lo = g; base = 0; }
    else if (g < E0 + E1) { ed = e1; E = E1; lo = g - E0; base = NPn; }
    else if (g < E0 + E1 + E2) { ed = e2; E = E2; lo = g - E0 - E1; base = NPn + NGn; }
    else return;
    atomicAdd(&cnt[base + ed[E + lo]], 1);
}

__global__ __launch_bounds__(256) void scan_pass1(const int* __restrict__ cnt, int n,
                                                  int* __restrict__ partial) {
    int base = blockIdx.x * 1024 + threadIdx.x * 4;
    int s = 0;
    if (base + 3 < n) {
        int4 v = *(const int4*)&cnt[base];
        s = v.x + v.y + v.z + v.w;
    } else {
        for (int i = 0; i < 4; ++i) if (base + i < n) s += cnt[base + i];
    }
    __shared__ int red[256];
    red[threadIdx.x] = s;
    __syncthreads();
    for (int off = 128; off; off >>= 1) {
        if (threadIdx.x < off) red[threadIdx.x] += red[threadIdx.x + off];
        __syncthreads();
    }
    if (threadIdx.x == 0) partial[blockIdx.x] = red[0];
}

__global__ __launch_bounds__(1024) void scan_pass2(int* __restrict__ partial, int nb,
                                                   int* __restrict__ total_out) {
    __shared__ int sh[1024];
    int t = threadIdx.x;
    int v = (t < nb) ? partial[t] : 0;
    sh[t] = v;
    __syncthreads();
    for (int off = 1; off < 1024; off <<= 1) {
        int u = (t >= off) ? sh[t - off] : 0;
        __syncthreads();
        sh[t] += u;
        __syncthreads();
    }
    if (t < nb) partial[t] = sh[t] - v;   // exclusive
    if (t == 1023) *total_out = sh[1023];
}

__global__ __launch_bounds__(256) void scan_pass3(const int* __restrict__ cnt, int n,
                                                  const int* __restrict__ partial,
                                                  int* __restrict__ rowptr) {
    int t = threadIdx.x;
    int base = blockIdx.x * 1024 + t * 4;
    int v[4];
    int s = 0;
    for (int i = 0; i < 4; ++i) {
        v[i] = (base + i < n) ? cnt[base + i] : 0;
        s += v[i];
    }
    __shared__ int sh[256];
    sh[t] = s;
    __syncthreads();
    for (int off = 1; off < 256; off <<= 1) {
        int u = (t >= off) ? sh[t - off] : 0;
        __syncthreads();
        sh[t] += u;
        __syncthreads();
    }
    int run = partial[blockIdx.x] + sh[t] - s;
    for (int i = 0; i < 4; ++i) {
        int idx = base + i;
        if (idx < n) {
            rowptr[idx] = run;
            run += v[i];
        }
    }
}

// bin cursor init: bin b's frontier starts at rowptr[b*BINW] (bins partition col space)
__global__ __launch_bounds__(256) void bin_init_kernel(const int* __restrict__ rowptr,
                                                       int* __restrict__ bin_cur,
                                                       int nbins, int n_tot) {
    int b = blockIdx.x * 256 + threadIdx.x;
    if (b < nbins) {
        int node = b << BSH;
        if (node > n_tot) node = n_tot;
        bin_cur[b] = rowptr[node];
    }
}

// pass A: scatter edges into per-bin contiguous regions of temp.
// Concurrent writers to a bin write ADJACENT slots -> frontier lines fill fully (no 16x amp).
// payload: src | (local_dst << 16)  (valid: all node indices < 50000 < 2^16, BINW=128)
__global__ __launch_bounds__(256) void bin_scatter_kernel(
    const int* __restrict__ e0, int E0, const int* __restrict__ e1, int E1,
    const int* __restrict__ e2, int E2, int* __restrict__ bin_cur,
    int* __restrict__ temp, int NPn, int NGn) {
    int g = blockIdx.x * 256 + threadIdx.x;
    const int* ed; int E, lo, base;
    if (g < E0) { ed = e0; E = E0; lo = g; base = 0; }
    else if (g < E0 + E1) { ed = e1; E = E1; lo = g - E0; base = NPn; }
    else if (g < E0 + E1 + E2) { ed = e2; E = E2; lo = g - E0 - E1; base = NPn + NGn; }
    else return;
    int src = ed[lo];
    int gdst = base + ed[E + lo];
    int pos = atomicAdd(&bin_cur[gdst >> BSH], 1);
    temp[pos] = src | ((gdst & (BINW - 1)) << 16);
}

// pass B: per-bin LDS counting sort; col written fully coalesced.
__global__ __launch_bounds__(256) void bin_sort_kernel(
    const int* __restrict__ rowptr, const int* __restrict__ temp,
    int* __restrict__ col, int n_tot) {
    __shared__ int srt[BCAP];
    __shared__ int cur[BINW];
    __shared__ int rp[BINW + 1];
    int b = blockIdx.x;
    int start = b << BSH;
    int nodes = n_tot - start; if (nodes > BINW) nodes = BINW;
    int t = threadIdx.x;
    for (int i = t; i <= nodes; i += 256) rp[i] = rowptr[start + i];
    __syncthreads();
    int base = rp[0];
    int count = rp[nodes] - base;
    if (t < nodes) cur[t] = rp[t + 1 - 1] - base;   // exclusive start of node t within bin
    __syncthreads();
    if (count <= BCAP) {
        for (int i = t; i < count; i += 256) {
            int v = temp[base + i];
            int p = atomicAdd(&cur[(v >> 16) & (BINW - 1)], 1);
            srt[p] = v & 0xFFFF;
        }
        __syncthreads();
        for (int i = t; i < count; i += 256) col[base + i] = srt[i];
    } else {  // fallback (not expected with this data): direct global scatter
        for (int i = t; i < count; i += 256) {
            int v = temp[base + i];
            int p = atomicAdd(&cur[(v >> 16) & (BINW - 1)], 1);
            col[base + p] = v & 0xFFFF;
        }
    }
}

// ---------------- W pack: fp32 [k][n] -> MFMA B-fragment order, split bf16 hi/lo ----------------
// 15 matrices (5 per layer: Wl_isa, Wl_rev, Wsum=Wr_isa+Wr_rev, Wl_rel, Wr_rel).
// B-operand layout: n = ct*16 + (lane&15), k = kc*32 + (lane>>4)*8 + j.

struct WSrc { const float* a[15]; const float* b[15]; };

__global__ __launch_bounds__(256) void pack_w_kernel(WSrc src, short* __restrict__ whi,
                                                     short* __restrict__ wlo) {
    int idx = blockIdx.x * 256 + threadIdx.x;   // (mat, kc, ct, lane)
    if (idx >= 15 * 4 * 8 * 64) return;
    int lane = idx & 63;
    int ct = (idx >> 6) & 7;
    int kc = (idx >> 9) & 3;
    int mat = idx >> 11;
    const float* A = src.a[mat];
    const float* Bp = src.b[mat];
    int n = ct * 16 + (lane & 15);
    int kbase = kc * 32 + (lane >> 4) * 8;
    size_t o = (size_t)idx * 8;
    for (int j = 0; j < 8; ++j) {
        float v = A[(size_t)(kbase + j) * H + n];
        if (Bp) v += Bp[(size_t)(kbase + j) * H + n];
        short h = f2bf(v);
        whi[o + j] = h;
        wlo[o + j] = f2bf(v - bf2f(h));
    }
}

// ---------------- merged per-layer segment mean ----------------
// Wave w < NP: isa-mean(xp)->M1[w] AND rev-mean(xg)->M2[w]. Wave in [NP,NP+NG): rel-mean(xp)->M3.

__device__ __forceinline__ float2 seg_mean(const float* __restrict__ x,
                                           const int* __restrict__ col,
                                           int beg, int end, int off) {
    float ax[8], ay[8];
#pragma unroll
    for (int i = 0; i < 8; ++i) { ax[i] = 0.f; ay[i] = 0.f; }
    int e = beg;
    for (; e + 7 < end; e += 8) {
        int s[8];
#pragma unroll
        for (int i = 0; i < 8; ++i) s[i] = col[e + i];
#pragma unroll
        for (int i = 0; i < 8; ++i) {
            float2 v = *(const float2*)&x[(size_t)s[i] * H + off];
            ax[i] += v.x; ay[i] += v.y;
        }
    }
    for (; e < end; ++e) {
        float2 v = *(const float2*)&x[(size_t)col[e] * H + off];
        ax[0] += v.x; ay[0] += v.y;
    }
    float sx = ((ax[0] + ax[1]) + (ax[2] + ax[3])) + ((ax[4] + ax[5]) + (ax[6] + ax[7]));
    float sy = ((ay[0] + ay[1]) + (ay[2] + ay[3])) + ((ay[4] + ay[5]) + (ay[6] + ay[7]));
    int c = end - beg; if (c < 1) c = 1;
    float inv = 1.0f / (float)c;
    return (float2){sx * inv, sy * inv};
}

__global__ __launch_bounds__(256) void agg_all_kernel(
    const float* __restrict__ xp, const float* __restrict__ xg,
    const int* __restrict__ rowptr, const int* __restrict__ col,
    float* __restrict__ M1, float* __restrict__ M2, float* __restrict__ M3,
    int NPn, int NGn) {
    int w = (blockIdx.x << 2) + (threadIdx.x >> 6);
    int lane = threadIdx.x & 63;
    int off = lane * 2;
    if (w < NPn) {
        float2 r1 = seg_mean(xp, col, rowptr[w], rowptr[w + 1], off);
        *(float2*)&M1[(size_t)w * H + off] = r1;
        int b = NPn + NGn + w;
        float2 r2 = seg_mean(xg, col, rowptr[b], rowptr[b + 1], off);
        *(float2*)&M2[(size_t)w * H + off] = r2;
    } else if (w < NPn + NGn) {
        float2 r3 = seg_mean(xp, col, rowptr[w], rowptr[w + 1], off);
        *(float2*)&M3[(size_t)(w - NPn) * H + off] = r3;
    }
}

// ---------------- split-bf16 MFMA GEMM, double-buffered B prefetch (proven R6) ----------------

template <int NIN>
__global__ __launch_bounds__(256, 3) void gemm_mfma(
    const float* __restrict__ A0, const float* __restrict__ A1, const float* __restrict__ A2,
    const short* __restrict__ whi, const short* __restrict__ wlo,
    int mat0, int mat1, int mat2,
    const float* __restrict__ b0, const float* __restrict__ b1,
    float* __restrict__ out, int n_rows, int relu) {
    __shared__ short Ahi[64 * RS];
    __shared__ short Alo[64 * RS];
    const int tid = threadIdx.x;
    const int lane = tid & 63;
    const int wave = tid >> 6;
    const int r0 = blockIdx.x * 64;
    const int ct0 = wave * 2;
    const int m16 = lane & 15;
    const int acol = (lane >> 4) * 8;

    f32x4 acc[4][2];
#pragma unroll
    for (int mt = 0; mt < 4; ++mt)
#pragma unroll
        for (int c = 0; c < 2; ++c) acc[mt][c] = (f32x4){0.f, 0.f, 0.f, 0.f};

    const float* Aarr[3] = {A0, A1, A2};
    const int marr[3] = {mat0, mat1, mat2};

    short8 bh[2][2], bl[2][2];
    {
        const short* wh = whi + (size_t)marr[0] * (H * H);
        const short* wl = wlo + (size_t)marr[0] * (H * H);
        size_t f0 = ((size_t)ct0 * 64 + lane) * 8;
        bh[0][0] = *(const short8*)&wh[f0];
        bh[0][1] = *(const short8*)&wh[f0 + 512];
        bl[0][0] = *(const short8*)&wl[f0];
        bl[0][1] = *(const short8*)&wl[f0 + 512];
    }

#pragma unroll
    for (int m = 0; m < NIN; ++m) {
        const float* __restrict__ A = Aarr[m];
        const short* __restrict__ wh = whi + (size_t)marr[m] * (H * H);
        const short* __restrict__ wl = wlo + (size_t)marr[m] * (H * H);
        __syncthreads();
#pragma unroll
        for (int i = 0; i < 8; ++i) {
            int f = tid + i * 256;
            int row = f >> 5;
            int c4 = (f & 31) * 4;
            int gr = r0 + row;
            if (gr >= n_rows) gr = n_rows - 1;
            float4 v = *(const float4*)&A[(size_t)gr * H + c4];
            short h0 = f2bf(v.x), h1 = f2bf(v.y), h2 = f2bf(v.z), h3 = f2bf(v.w);
            *(short4v*)&Ahi[row * RS + c4] = (short4v){h0, h1, h2, h3};
            *(short4v*)&Alo[row * RS + c4] =
                (short4v){f2bf(v.x - bf2f(h0)), f2bf(v.y - bf2f(h1)),
                          f2bf(v.z - bf2f(h2)), f2bf(v.w - bf2f(h3))};
        }
        __syncthreads();
#pragma unroll
        for (int kc = 0; kc < 4; ++kc) {
            if (kc < 3) {
                int nb = (kc + 1) & 1;
                size_t f = ((size_t)((kc + 1) * 8 + ct0) * 64 + lane) * 8;
                bh[nb][0] = *(const short8*)&wh[f];
                bh[nb][1] = *(const short8*)&wh[f + 512];
                bl[nb][0] = *(const short8*)&wl[f];
                bl[nb][1] = *(const short8*)&wl[f + 512];
            } else if (m + 1 < NIN) {
                const short* wh2 = whi + (size_t)marr[m + 1] * (H * H);
                const short* wl2 = wlo + (size_t)marr[m + 1] * (H * H);
                size_t f = ((size_t)ct0 * 64 + lane) * 8;
                bh[0][0] = *(const short8*)&wh2[f];
                bh[0][1] = *(const short8*)&wh2[f + 512];
                bl[0][0] = *(const short8*)&wl2[f];
                bl[0][1] = *(const short8*)&wl2[f + 512];
            }
            int cb = kc & 1;
#pragma unroll
            for (int mt = 0; mt < 4; ++mt) {
                short8 ah = *(const short8*)&Ahi[(mt * 16 + m16) * RS + kc * 32 + acol];
                short8 al = *(const short8*)&Alo[(mt * 16 + m16) * RS + kc * 32 + acol];
#pragma unroll
                for (int c = 0; c < 2; ++c) {
                    acc[mt][c] = __builtin_amdgcn_mfma_f32_16x16x32_bf16(ah, bh[cb][c], acc[mt][c], 0, 0, 0);
                    acc[mt][c] = __builtin_amdgcn_mfma_f32_16x16x32_bf16(al, bh[cb][c], acc[mt][c], 0, 0, 0);
                    acc[mt][c] = __builtin_amdgcn_mfma_f32_16x16x32_bf16(ah, bl[cb][c], acc[mt][c], 0, 0, 0);
                }
            }
        }
    }

    const int rquad = (lane >> 4) * 4;
    const int ncol = lane & 15;
#pragma unroll
    for (int c = 0; c < 2; ++c) {
        int n = (ct0 + c) * 16 + ncol;
        float bs = b0[n];
        if (b1) bs += b1[n];
#pragma unroll
        for (int mt = 0; mt < 4; ++mt) {
#pragma unroll
            for (int reg = 0; reg < 4; ++reg) {
                int gr = r0 + mt * 16 + rquad + reg;
                if (gr < n_rows) {
                    float v = acc[mt][c][reg] + bs;
                    if (relu) v = v > 0.f ? v : 0.01f * v;
                    out[(size_t)gr * H + n] = v;
                }
            }
        }
    }
}

// ---------------- edge decoder: sigmoid(dot(xp[i], xg[j])) ----------------

__global__ __launch_bounds__(256) void scores_kernel(const float* __restrict__ xp,
                                                     const float* __restrict__ xg,
                                                     const int* __restrict__ eli, int E,
                                                     float* __restrict__ out) {
    int lane16 = threadIdx.x & 15;
    int sub = threadIdx.x >> 4;     // 16 edges per block
    int e = blockIdx.x * 16 + sub;
    if (e >= E) return;
    int ip = eli[e];
    int ig = eli[E + e];
    const float4* p = (const float4*)&xp[(size_t)ip * H];
    const float4* g = (const float4*)&xg[(size_t)ig * H];
    float4 a0 = p[lane16], a1 = p[lane16 + 16];
    float4 b0 = g[lane16], b1 = g[lane16 + 16];
    float s = a0.x * b0.x + a0.y * b0.y + a0.z * b0.z + a0.w * b0.w
            + a1.x * b1.x + a1.y * b1.y + a1.z * b1.z + a1.w * b1.w;
#pragma unroll
    for (int off = 8; off; off >>= 1) s += __shfl_xor(s, off, 16);
    if (lane16 == 0) out[e] = 1.0f / (1.0f + expf(-s));
}

// ---------------- host ----------------

extern "C" void kernel_launch(void* const* d_in, const int* in_sizes, int n_in,
                              void* d_out, int out_size, void* d_ws, size_t ws_size,
                              hipStream_t stream) {
    const float* x_pheno = (const float*)d_in[0];
    const float* x_gene  = (const float*)d_in[1];
    const float* Wl_isa  = (const float*)d_in[2];
    const float* bl_isa  = (const float*)d_in[3];
    const float* Wr_isa  = (const float*)d_in[4];
    const float* Wl_rel  = (const float*)d_in[5];
    const float* bl_rel  = (const float*)d_in[6];
    const float* Wr_rel  = (const float*)d_in[7];
    const float* Wl_rev  = (const float*)d_in[8];
    const float* bl_rev  = (const float*)d_in[9];
    const float* Wr_rev  = (const float*)d_in[10];
    const int* e_isa = (const int*)d_in[11];
    const int* e_rel = (const int*)d_in[12];
    const int* e_rev = (const int*)d_in[13];
    const int* e_lbl = (const int*)d_in[14];
    const int E_isa = in_sizes[11] / 2;
    const int E_rel = in_sizes[12] / 2;
    const int E_rev = in_sizes[13] / 2;
    const int E_lbl = in_sizes[14] / 2;
    const int NP = in_sizes[0] / H;
    const int NG = in_sizes[1] / H;
    const int NMAX = NP > NG ? NP : NG;
    const int n_tot = NP + NG + NP;
    const int E_tot = E_isa + E_rel + E_rev;
    const int nb = (n_tot + 1023) / 1024;
    const int nbins = (n_tot + BINW - 1) / BINW;

    char* ws = (char*)d_ws;
    auto alloc = [&](size_t bytes) -> char* {
        char* p = ws;
        ws += (bytes + 255) & ~(size_t)255;
        return p;
    };
    float* B[5];
    for (int i = 0; i < 5; ++i) B[i] = (float*)alloc((size_t)NMAX * H * sizeof(float));
    int* cnt     = (int*)alloc((size_t)n_tot * 4);
    int* rowptr  = (int*)alloc((size_t)(n_tot + 1) * 4);
    int* col     = (int*)alloc((size_t)E_tot * 4);
    int* temp    = (int*)alloc((size_t)E_tot * 4);
    int* bin_cur = (int*)alloc((size_t)nbins * 4);
    int* partial = (int*)alloc((size_t)1024 * 4);
    short* whi = (short*)alloc((size_t)15 * H * H * sizeof(short));
    short* wlo = (short*)alloc((size_t)15 * H * H * sizeof(short));

    // ---- CSR build (every call; ws is re-poisoned by the harness) ----
    hipMemsetAsync(cnt, 0, (size_t)n_tot * 4, stream);
    count_all_kernel<<<(E_tot + 255) / 256, 256, 0, stream>>>(
        e_isa, E_isa, e_rel, E_rel, e_rev, E_rev, cnt, NP, NG);
    scan_pass1<<<nb, 256, 0, stream>>>(cnt, n_tot, partial);
    scan_pass2<<<1, 1024, 0, stream>>>(partial, nb, &rowptr[n_tot]);
    scan_pass3<<<nb, 256, 0, stream>>>(cnt, n_tot, partial, rowptr);
    bin_init_kernel<<<(nbins + 255) / 256, 256, 0, stream>>>(rowptr, bin_cur, nbins, n_tot);
    bin_scatter_kernel<<<(E_tot + 255) / 256, 256, 0, stream>>>(
        e_isa, E_isa, e_rel, E_rel, e_rev, E_rev, bin_cur, temp, NP, NG);
    bin_sort_kernel<<<nbins, 256, 0, stream>>>(rowptr, temp, col, n_tot);

    // ---- W pack: per layer slots {Wl_isa, Wl_rev, Wsum=Wr_isa+Wr_rev, Wl_rel, Wr_rel} ----
    WSrc src;
    for (int l = 0; l < 3; ++l) {
        src.a[l * 5 + 0] = Wl_isa + (size_t)l * H * H;  src.b[l * 5 + 0] = nullptr;
        src.a[l * 5 + 1] = Wl_rev + (size_t)l * H * H;  src.b[l * 5 + 1] = nullptr;
        src.a[l * 5 + 2] = Wr_isa + (size_t)l * H * H;  src.b[l * 5 + 2] = Wr_rev + (size_t)l * H * H;
        src.a[l * 5 + 3] = Wl_rel + (size_t)l * H * H;  src.b[l * 5 + 3] = nullptr;
        src.a[l * 5 + 4] = Wr_rel + (size_t)l * H * H;  src.b[l * 5 + 4] = nullptr;
    }
    pack_w_kernel<<<(15 * 4 * 8 * 64 + 255) / 256, 256, 0, stream>>>(src, whi, wlo);

    // ---- 3 layers ----
    // buffers: layer0 M1=B0 M2=B1 M3=B2; layer1 M1=B3 M2=B1 M3=B4; layer2 M1=B0 M2=B1 M3=B2
    int mi[3] = {0, 3, 0}, mv[3] = {1, 1, 1}, mr[3] = {2, 4, 2};
    const float* xp = x_pheno;
    const float* xg = x_gene;
    for (int l = 0; l < 3; ++l) {
        float* M1 = B[mi[l]];
        float* M2 = B[mv[l]];
        float* M3 = B[mr[l]];
        agg_all_kernel<<<(NP + NG + 3) / 4, 256, 0, stream>>>(
            xp, xg, rowptr, col, M1, M2, M3, NP, NG);
        int relu = (l < 2) ? 1 : 0;
        const float* bli = bl_isa + (size_t)l * H;
        const float* blv = bl_rev + (size_t)l * H;
        const float* blr = bl_rel + (size_t)l * H;
        // new_p = M1@Wl_isa + M2@Wl_rev + xp@(Wr_isa+Wr_rev) + bl_isa + bl_rev -> M1 (in-place)
        gemm_mfma<3><<<(NP + 63) / 64, 256, 0, stream>>>(
            M1, M2, xp, whi, wlo, l * 5 + 0, l * 5 + 1, l * 5 + 2, bli, blv, M1, NP, relu);
        // new_g = M3@Wl_rel + xg@Wr_rel + bl_rel -> M3 (in-place)
        gemm_mfma<2><<<(NG + 63) / 64, 256, 0, stream>>>(
            M3, xg, nullptr, whi, wlo, l * 5 + 3, l * 5 + 4, 0, blr, nullptr, M3, NG, relu);
        xp = M1;
        xg = M3;
    }

    // ---- decoder ----
    scores_kernel<<<(E_lbl + 15) / 16, 256, 0, stream>>>(xp, xg, e_lbl, E_lbl, (float*)d_out);
}

// Round 9
// 985.010 us; speedup vs baseline: 1.7009x; 1.7009x over previous
//
#include <hip/hip_runtime.h>
#include <hip/hip_bf16.h>
#include <math.h>

#define H 128
#define RS 136    // LDS row stride in shorts (128 + 8 pad; keeps ds_read_b128 16B-aligned)
#define BSH 9     // bin shift: 512 nodes per bin
#define BINW 512
#define BCAP 11264  // max edges/bin for LDS sort (expected max ~10.6k at deg-20, 512 nodes)
#define KEDGE 4096  // edges per partition block
#define EPT 16      // edges per thread (KEDGE/256)
#define MAXBINS 1024

typedef __attribute__((ext_vector_type(8))) short short8;
typedef __attribute__((ext_vector_type(4))) short short4v;
typedef __attribute__((ext_vector_type(4))) float f32x4;

// fp32 -> bf16 (RNE); values here are finite (no NaN handling needed)
__device__ __forceinline__ short f2bf(float f) {
    unsigned u = __float_as_uint(f);
    u += 0x7fff + ((u >> 16) & 1);
    return (short)(u >> 16);
}
__device__ __forceinline__ float bf2f(short h) {
    return __uint_as_float(((unsigned)(unsigned short)h) << 16);
}

// ---------------- CSR build ----------------
// Node space concatenated: [NP(isa) | NG(rel) | NP(rev)].

__global__ __launch_bounds__(256) void count_all_kernel(
    const int* __restrict__ e0, int E0, const int* __restrict__ e1, int E1,
    const int* __restrict__ e2, int E2, int* __restrict__ cnt, int NPn, int NGn) {
    int g = blockIdx.x * 256 + threadIdx.x;
    const int* ed; int E, lo, base;
    if (g < E0) { ed = e0; E = E0; lo = g; base = 0; }
    else if (g < E0 + E1) { ed = e1; E = E1; lo = g - E0; base = NPn; }
    else if (g < E0 + E1 + E2) { ed = e2; E = E2; lo = g - E0 - E1; base = NPn + NGn; }
    else return;
    atomicAdd(&cnt[base + ed[E + lo]], 1);
}

__global__ __launch_bounds__(256) void scan_pass1(const int* __restrict__ cnt, int n,
                                                  int* __restrict__ partial) {
    int base = blockIdx.x * 1024 + threadIdx.x * 4;
    int s = 0;
    if (base + 3 < n) {
        int4 v = *(const int4*)&cnt[base];
        s = v.x + v.y + v.z + v.w;
    } else {
        for (int i = 0; i < 4; ++i) if (base + i < n) s += cnt[base + i];
    }
    __shared__ int red[256];
    red[threadIdx.x] = s;
    __syncthreads();
    for (int off = 128; off; off >>= 1) {
        if (threadIdx.x < off) red[threadIdx.x] += red[threadIdx.x + off];
        __syncthreads();
    }
    if (threadIdx.x == 0) partial[blockIdx.x] = red[0];
}

__global__ __launch_bounds__(1024) void scan_pass2(int* __restrict__ partial, int nb,
                                                   int* __restrict__ total_out) {
    __shared__ int sh[1024];
    int t = threadIdx.x;
    int v = (t < nb) ? partial[t] : 0;
    sh[t] = v;
    __syncthreads();
    for (int off = 1; off < 1024; off <<= 1) {
        int u = (t >= off) ? sh[t - off] : 0;
        __syncthreads();
        sh[t] += u;
        __syncthreads();
    }
    if (t < nb) partial[t] = sh[t] - v;   // exclusive
    if (t == 1023) *total_out = sh[1023];
}

__global__ __launch_bounds__(256) void scan_pass3(const int* __restrict__ cnt, int n,
                                                  const int* __restrict__ partial,
                                                  int* __restrict__ rowptr) {
    int t = threadIdx.x;
    int base = blockIdx.x * 1024 + t * 4;
    int v[4];
    int s = 0;
    for (int i = 0; i < 4; ++i) {
        v[i] = (base + i < n) ? cnt[base + i] : 0;
        s += v[i];
    }
    __shared__ int sh[256];
    sh[t] = s;
    __syncthreads();
    for (int off = 1; off < 256; off <<= 1) {
        int u = (t >= off) ? sh[t - off] : 0;
        __syncthreads();
        sh[t] += u;
        __syncthreads();
    }
    int run = partial[blockIdx.x] + sh[t] - s;
    for (int i = 0; i < 4; ++i) {
        int idx = base + i;
        if (idx < n) {
            rowptr[idx] = run;
            run += v[i];
        }
    }
}

// bin cursor init: bin b's frontier = rowptr[b*BINW]; PADDED to 1 counter per 64B line.
__global__ __launch_bounds__(256) void bin_init_kernel(const int* __restrict__ rowptr,
                                                       int* __restrict__ bin_cur,
                                                       int nbins, int n_tot) {
    int b = blockIdx.x * 256 + threadIdx.x;
    if (b < nbins) {
        int node = b << BSH;
        if (node > n_tot) node = n_tot;
        bin_cur[b * 16] = rowptr[node];
    }
}

// pass A: block-aggregated partition. Per block: LDS histogram over bins, ONE global
// atomicAdd per touched bin (reserve a contiguous run), then scatter from registers via
// LDS run-cursors. Global atomics: ~611*293 ~= 180k on 64B-strided counters (no false
// sharing, ~600/line over the whole kernel). Run length ~17 ints -> near-full line use.
// payload: src | (local_dst << 16)  (src < 2^16, local_dst < 512 -> bits 16..24)
__global__ __launch_bounds__(256) void bin_scatter_kernel(
    const int* __restrict__ e0, int E0, const int* __restrict__ e1, int E1,
    const int* __restrict__ e2, int E2, int* __restrict__ bin_cur,
    int* __restrict__ temp, int NPn, int NGn, int nbins, int E_tot) {
    __shared__ int hist[MAXBINS];
    __shared__ int cur[MAXBINS];
    int t = threadIdx.x;
    for (int i = t; i < nbins; i += 256) hist[i] = 0;
    __syncthreads();
    int vals[EPT], bins[EPT];
    int base_e = blockIdx.x * KEDGE;
#pragma unroll
    for (int j = 0; j < EPT; ++j) {
        int g = base_e + j * 256 + t;      // coalesced within each j-step
        int b = -1, v = 0;
        if (g < E_tot) {
            const int* ed; int E, lo, nbase;
            if (g < E0) { ed = e0; E = E0; lo = g; nbase = 0; }
            else if (g < E0 + E1) { ed = e1; E = E1; lo = g - E0; nbase = NPn; }
            else { ed = e2; E = E2; lo = g - E0 - E1; nbase = NPn + NGn; }
            int src = ed[lo];
            int gdst = nbase + ed[E + lo];
            v = src | ((gdst & (BINW - 1)) << 16);
            b = gdst >> BSH;
            atomicAdd(&hist[b], 1);        // LDS atomic
        }
        vals[j] = v;
        bins[j] = b;
    }
    __syncthreads();
    for (int i = t; i < nbins; i += 256) {
        int h = hist[i];
        cur[i] = h ? atomicAdd(&bin_cur[i * 16], h) : 0;   // reserve run; cur = global base
    }
    __syncthreads();
#pragma unroll
    for (int j = 0; j < EPT; ++j) {
        if (bins[j] >= 0) {
            int p = atomicAdd(&cur[bins[j]], 1);           // LDS atomic -> global slot
            temp[p] = vals[j];
        }
    }
}

// pass B: per-bin LDS counting sort; col written fully coalesced.
__global__ __launch_bounds__(256) void bin_sort_kernel(
    const int* __restrict__ rowptr, const int* __restrict__ temp,
    int* __restrict__ col, int n_tot) {
    __shared__ int srt[BCAP];
    __shared__ int cur[BINW];
    __shared__ int rp[BINW + 1];
    int b = blockIdx.x;
    int start = b << BSH;
    int nodes = n_tot - start; if (nodes > BINW) nodes = BINW;
    int t = threadIdx.x;
    for (int i = t; i <= nodes; i += 256) rp[i] = rowptr[start + i];
    __syncthreads();
    int base = rp[0];
    int count = rp[nodes] - base;
    for (int i = t; i < nodes; i += 256) cur[i] = rp[i] - base;  // local exclusive starts
    __syncthreads();
    if (count <= BCAP) {
        for (int i = t; i < count; i += 256) {
            int v = temp[base + i];
            int p = atomicAdd(&cur[(v >> 16) & (BINW - 1)], 1);
            srt[p] = v & 0xFFFF;
        }
        __syncthreads();
        for (int i = t; i < count; i += 256) col[base + i] = srt[i];
    } else {  // fallback (not expected): direct global scatter
        for (int i = t; i < count; i += 256) {
            int v = temp[base + i];
            int p = atomicAdd(&cur[(v >> 16) & (BINW - 1)], 1);
            col[base + p] = v & 0xFFFF;
        }
    }
}

// ---------------- W pack: fp32 [k][n] -> MFMA B-fragment order, split bf16 hi/lo ----------------
// 15 matrices (5 per layer: Wl_isa, Wl_rev, Wsum=Wr_isa+Wr_rev, Wl_rel, Wr_rel).
// B-operand layout: n = ct*16 + (lane&15), k = kc*32 + (lane>>4)*8 + j.

struct WSrc { const float* a[15]; const float* b[15]; };

__global__ __launch_bounds__(256) void pack_w_kernel(WSrc src, short* __restrict__ whi,
                                                     short* __restrict__ wlo) {
    int idx = blockIdx.x * 256 + threadIdx.x;   // (mat, kc, ct, lane)
    if (idx >= 15 * 4 * 8 * 64) return;
    int lane = idx & 63;
    int ct = (idx >> 6) & 7;
    int kc = (idx >> 9) & 3;
    int mat = idx >> 11;
    const float* A = src.a[mat];
    const float* Bp = src.b[mat];
    int n = ct * 16 + (lane & 15);
    int kbase = kc * 32 + (lane >> 4) * 8;
    size_t o = (size_t)idx * 8;
    for (int j = 0; j < 8; ++j) {
        float v = A[(size_t)(kbase + j) * H + n];
        if (Bp) v += Bp[(size_t)(kbase + j) * H + n];
        short h = f2bf(v);
        whi[o + j] = h;
        wlo[o + j] = f2bf(v - bf2f(h));
    }
}

// ---------------- merged per-layer segment mean ----------------
// Wave w < NP: isa-mean(xp)->M1[w] AND rev-mean(xg)->M2[w]. Wave in [NP,NP+NG): rel-mean(xp)->M3.

__device__ __forceinline__ float2 seg_mean(const float* __restrict__ x,
                                           const int* __restrict__ col,
                                           int beg, int end, int off) {
    float ax[8], ay[8];
#pragma unroll
    for (int i = 0; i < 8; ++i) { ax[i] = 0.f; ay[i] = 0.f; }
    int e = beg;
    for (; e + 7 < end; e += 8) {
        int s[8];
#pragma unroll
        for (int i = 0; i < 8; ++i) s[i] = col[e + i];
#pragma unroll
        for (int i = 0; i < 8; ++i) {
            float2 v = *(const float2*)&x[(size_t)s[i] * H + off];
            ax[i] += v.x; ay[i] += v.y;
        }
    }
    for (; e < end; ++e) {
        float2 v = *(const float2*)&x[(size_t)col[e] * H + off];
        ax[0] += v.x; ay[0] += v.y;
    }
    float sx = ((ax[0] + ax[1]) + (ax[2] + ax[3])) + ((ax[4] + ax[5]) + (ax[6] + ax[7]));
    float sy = ((ay[0] + ay[1]) + (ay[2] + ay[3])) + ((ay[4] + ay[5]) + (ay[6] + ay[7]));
    int c = end - beg; if (c < 1) c = 1;
    float inv = 1.0f / (float)c;
    return (float2){sx * inv, sy * inv};
}

__global__ __launch_bounds__(256) void agg_all_kernel(
    const float* __restrict__ xp, const float* __restrict__ xg,
    const int* __restrict__ rowptr, const int* __restrict__ col,
    float* __restrict__ M1, float* __restrict__ M2, float* __restrict__ M3,
    int NPn, int NGn) {
    int w = (blockIdx.x << 2) + (threadIdx.x >> 6);
    int lane = threadIdx.x & 63;
    int off = lane * 2;
    if (w < NPn) {
        float2 r1 = seg_mean(xp, col, rowptr[w], rowptr[w + 1], off);
        *(float2*)&M1[(size_t)w * H + off] = r1;
        int b = NPn + NGn + w;
        float2 r2 = seg_mean(xg, col, rowptr[b], rowptr[b + 1], off);
        *(float2*)&M2[(size_t)w * H + off] = r2;
    } else if (w < NPn + NGn) {
        float2 r3 = seg_mean(xp, col, rowptr[w], rowptr[w + 1], off);
        *(float2*)&M3[(size_t)(w - NPn) * H + off] = r3;
    }
}

// ---------------- split-bf16 MFMA GEMM, double-buffered B prefetch (proven R6) ----------------

template <int NIN>
__global__ __launch_bounds__(256, 3) void gemm_mfma(
    const float* __restrict__ A0, const float* __restrict__ A1, const float* __restrict__ A2,
    const short* __restrict__ whi, const short* __restrict__ wlo,
    int mat0, int mat1, int mat2,
    const float* __restrict__ b0, const float* __restrict__ b1,
    float* __restrict__ out, int n_rows, int relu) {
    __shared__ short Ahi[64 * RS];
    __shared__ short Alo[64 * RS];
    const int tid = threadIdx.x;
    const int lane = tid & 63;
    const int wave = tid >> 6;
    const int r0 = blockIdx.x * 64;
    const int ct0 = wave * 2;
    const int m16 = lane & 15;
    const int acol = (lane >> 4) * 8;

    f32x4 acc[4][2];
#pragma unroll
    for (int mt = 0; mt < 4; ++mt)
#pragma unroll
        for (int c = 0; c < 2; ++c) acc[mt][c] = (f32x4){0.f, 0.f, 0.f, 0.f};

    const float* Aarr[3] = {A0, A1, A2};
    const int marr[3] = {mat0, mat1, mat2};

    short8 bh[2][2], bl[2][2];
    {
        const short* wh = whi + (size_t)marr[0] * (H * H);
        const short* wl = wlo + (size_t)marr[0] * (H * H);
        size_t f0 = ((size_t)ct0 * 64 + lane) * 8;
        bh[0][0] = *(const short8*)&wh[f0];
        bh[0][1] = *(const short8*)&wh[f0 + 512];
        bl[0][0] = *(const short8*)&wl[f0];
        bl[0][1] = *(const short8*)&wl[f0 + 512];
    }

#pragma unroll
    for (int m = 0; m < NIN; ++m) {
        const float* __restrict__ A = Aarr[m];
        const short* __restrict__ wh = whi + (size_t)marr[m] * (H * H);
        const short* __restrict__ wl = wlo + (size_t)marr[m] * (H * H);
        __syncthreads();
#pragma unroll
        for (int i = 0; i < 8; ++i) {
            int f = tid + i * 256;
            int row = f >> 5;
            int c4 = (f & 31) * 4;
            int gr = r0 + row;
            if (gr >= n_rows) gr = n_rows - 1;
            float4 v = *(const float4*)&A[(size_t)gr * H + c4];
            short h0 = f2bf(v.x), h1 = f2bf(v.y), h2 = f2bf(v.z), h3 = f2bf(v.w);
            *(short4v*)&Ahi[row * RS + c4] = (short4v){h0, h1, h2, h3};
            *(short4v*)&Alo[row * RS + c4] =
                (short4v){f2bf(v.x - bf2f(h0)), f2bf(v.y - bf2f(h1)),
                          f2bf(v.z - bf2f(h2)), f2bf(v.w - bf2f(h3))};
        }
        __syncthreads();
#pragma unroll
        for (int kc = 0; kc < 4; ++kc) {
            if (kc < 3) {
                int nb = (kc + 1) & 1;
                size_t f = ((size_t)((kc + 1) * 8 + ct0) * 64 + lane) * 8;
                bh[nb][0] = *(const short8*)&wh[f];
                bh[nb][1] = *(const short8*)&wh[f + 512];
                bl[nb][0] = *(const short8*)&wl[f];
                bl[nb][1] = *(const short8*)&wl[f + 512];
            } else if (m + 1 < NIN) {
                const short* wh2 = whi + (size_t)marr[m + 1] * (H * H);
                const short* wl2 = wlo + (size_t)marr[m + 1] * (H * H);
                size_t f = ((size_t)ct0 * 64 + lane) * 8;
                bh[0][0] = *(const short8*)&wh2[f];
                bh[0][1] = *(const short8*)&wh2[f + 512];
                bl[0][0] = *(const short8*)&wl2[f];
                bl[0][1] = *(const short8*)&wl2[f + 512];
            }
            int cb = kc & 1;
#pragma unroll
            for (int mt = 0; mt < 4; ++mt) {
                short8 ah = *(const short8*)&Ahi[(mt * 16 + m16) * RS + kc * 32 + acol];
                short8 al = *(const short8*)&Alo[(mt * 16 + m16) * RS + kc * 32 + acol];
#pragma unroll
                for (int c = 0; c < 2; ++c) {
                    acc[mt][c] = __builtin_amdgcn_mfma_f32_16x16x32_bf16(ah, bh[cb][c], acc[mt][c], 0, 0, 0);
                    acc[mt][c] = __builtin_amdgcn_mfma_f32_16x16x32_bf16(al, bh[cb][c], acc[mt][c], 0, 0, 0);
                    acc[mt][c] = __builtin_amdgcn_mfma_f32_16x16x32_bf16(ah, bl[cb][c], acc[mt][c], 0, 0, 0);
                }
            }
        }
    }

    const int rquad = (lane >> 4) * 4;
    const int ncol = lane & 15;
#pragma unroll
    for (int c = 0; c < 2; ++c) {
        int n = (ct0 + c) * 16 + ncol;
        float bs = b0[n];
        if (b1) bs += b1[n];
#pragma unroll
        for (int mt = 0; mt < 4; ++mt) {
#pragma unroll
            for (int reg = 0; reg < 4; ++reg) {
                int gr = r0 + mt * 16 + rquad + reg;
                if (gr < n_rows) {
                    float v = acc[mt][c][reg] + bs;
                    if (relu) v = v > 0.f ? v : 0.01f * v;
                    out[(size_t)gr * H + n] = v;
                }
            }
        }
    }
}

// ---------------- edge decoder: sigmoid(dot(xp[i], xg[j])) ----------------

__global__ __launch_bounds__(256) void scores_kernel(const float* __restrict__ xp,
                                                     const float* __restrict__ xg,
                                                     const int* __restrict__ eli, int E,
                                                     float* __restrict__ out) {
    int lane16 = threadIdx.x & 15;
    int sub = threadIdx.x >> 4;     // 16 edges per block
    int e = blockIdx.x * 16 + sub;
    if (e >= E) return;
    int ip = eli[e];
    int ig = eli[E + e];
    const float4* p = (const float4*)&xp[(size_t)ip * H];
    const float4* g = (const float4*)&xg[(size_t)ig * H];
    float4 a0 = p[lane16], a1 = p[lane16 + 16];
    float4 b0 = g[lane16], b1 = g[lane16 + 16];
    float s = a0.x * b0.x + a0.y * b0.y + a0.z * b0.z + a0.w * b0.w
            + a1.x * b1.x + a1.y * b1.y + a1.z * b1.z + a1.w * b1.w;
#pragma unroll
    for (int off = 8; off; off >>= 1) s += __shfl_xor(s, off, 16);
    if (lane16 == 0) out[e] = 1.0f / (1.0f + expf(-s));
}

// ---------------- host ----------------

extern "C" void kernel_launch(void* const* d_in, const int* in_sizes, int n_in,
                              void* d_out, int out_size, void* d_ws, size_t ws_size,
                              hipStream_t stream) {
    const float* x_pheno = (const float*)d_in[0];
    const float* x_gene  = (const float*)d_in[1];
    const float* Wl_isa  = (const float*)d_in[2];
    const float* bl_isa  = (const float*)d_in[3];
    const float* Wr_isa  = (const float*)d_in[4];
    const float* Wl_rel  = (const float*)d_in[5];
    const float* bl_rel  = (const float*)d_in[6];
    const float* Wr_rel  = (const float*)d_in[7];
    const float* Wl_rev  = (const float*)d_in[8];
    const float* bl_rev  = (const float*)d_in[9];
    const float* Wr_rev  = (const float*)d_in[10];
    const int* e_isa = (const int*)d_in[11];
    const int* e_rel = (const int*)d_in[12];
    const int* e_rev = (const int*)d_in[13];
    const int* e_lbl = (const int*)d_in[14];
    const int E_isa = in_sizes[11] / 2;
    const int E_rel = in_sizes[12] / 2;
    const int E_rev = in_sizes[13] / 2;
    const int E_lbl = in_sizes[14] / 2;
    const int NP = in_sizes[0] / H;
    const int NG = in_sizes[1] / H;
    const int NMAX = NP > NG ? NP : NG;
    const int n_tot = NP + NG + NP;
    const int E_tot = E_isa + E_rel + E_rev;
    const int nb = (n_tot + 1023) / 1024;
    const int nbins = (n_tot + BINW - 1) / BINW;

    char* ws = (char*)d_ws;
    auto alloc = [&](size_t bytes) -> char* {
        char* p = ws;
        ws += (bytes + 255) & ~(size_t)255;
        return p;
    };
    float* B[5];
    for (int i = 0; i < 5; ++i) B[i] = (float*)alloc((size_t)NMAX * H * sizeof(float));
    int* cnt     = (int*)alloc((size_t)n_tot * 4);
    int* rowptr  = (int*)alloc((size_t)(n_tot + 1) * 4);
    int* col     = (int*)alloc((size_t)E_tot * 4);
    int* temp    = (int*)alloc((size_t)E_tot * 4);
    int* bin_cur = (int*)alloc((size_t)nbins * 16 * 4);   // 64B-strided counters
    int* partial = (int*)alloc((size_t)1024 * 4);
    short* whi = (short*)alloc((size_t)15 * H * H * sizeof(short));
    short* wlo = (short*)alloc((size_t)15 * H * H * sizeof(short));

    // ---- CSR build (every call; ws is re-poisoned by the harness) ----
    hipMemsetAsync(cnt, 0, (size_t)n_tot * 4, stream);
    count_all_kernel<<<(E_tot + 255) / 256, 256, 0, stream>>>(
        e_isa, E_isa, e_rel, E_rel, e_rev, E_rev, cnt, NP, NG);
    scan_pass1<<<nb, 256, 0, stream>>>(cnt, n_tot, partial);
    scan_pass2<<<1, 1024, 0, stream>>>(partial, nb, &rowptr[n_tot]);
    scan_pass3<<<nb, 256, 0, stream>>>(cnt, n_tot, partial, rowptr);
    bin_init_kernel<<<(nbins + 255) / 256, 256, 0, stream>>>(rowptr, bin_cur, nbins, n_tot);
    bin_scatter_kernel<<<(E_tot + KEDGE - 1) / KEDGE, 256, 0, stream>>>(
        e_isa, E_isa, e_rel, E_rel, e_rev, E_rev, bin_cur, temp, NP, NG, nbins, E_tot);
    bin_sort_kernel<<<nbins, 256, 0, stream>>>(rowptr, temp, col, n_tot);

    // ---- W pack: per layer slots {Wl_isa, Wl_rev, Wsum=Wr_isa+Wr_rev, Wl_rel, Wr_rel} ----
    WSrc src;
    for (int l = 0; l < 3; ++l) {
        src.a[l * 5 + 0] = Wl_isa + (size_t)l * H * H;  src.b[l * 5 + 0] = nullptr;
        src.a[l * 5 + 1] = Wl_rev + (size_t)l * H * H;  src.b[l * 5 + 1] = nullptr;
        src.a[l * 5 + 2] = Wr_isa + (size_t)l * H * H;  src.b[l * 5 + 2] = Wr_rev + (size_t)l * H * H;
        src.a[l * 5 + 3] = Wl_rel + (size_t)l * H * H;  src.b[l * 5 + 3] = nullptr;
        src.a[l * 5 + 4] = Wr_rel + (size_t)l * H * H;  src.b[l * 5 + 4] = nullptr;
    }
    pack_w_kernel<<<(15 * 4 * 8 * 64 + 255) / 256, 256, 0, stream>>>(src, whi, wlo);

    // ---- 3 layers ----
    // buffers: layer0 M1=B0 M2=B1 M3=B2; layer1 M1=B3 M2=B1 M3=B4; layer2 M1=B0 M2=B1 M3=B2
    int mi[3] = {0, 3, 0}, mv[3] = {1, 1, 1}, mr[3] = {2, 4, 2};
    const float* xp = x_pheno;
    const float* xg = x_gene;
    for (int l = 0; l < 3; ++l) {
        float* M1 = B[mi[l]];
        float* M2 = B[mv[l]];
        float* M3 = B[mr[l]];
        agg_all_kernel<<<(NP + NG + 3) / 4, 256, 0, stream>>>(
            xp, xg, rowptr, col, M1, M2, M3, NP, NG);
        int relu = (l < 2) ? 1 : 0;
        const float* bli = bl_isa + (size_t)l * H;
        const float* blv = bl_rev + (size_t)l * H;
        const float* blr = bl_rel + (size_t)l * H;
        // new_p = M1@Wl_isa + M2@Wl_rev + xp@(Wr_isa+Wr_rev) + bl_isa + bl_rev -> M1 (in-place)
        gemm_mfma<3><<<(NP + 63) / 64, 256, 0, stream>>>(
            M1, M2, xp, whi, wlo, l * 5 + 0, l * 5 + 1, l * 5 + 2, bli, blv, M1, NP, relu);
        // new_g = M3@Wl_rel + xg@Wr_rel + bl_rel -> M3 (in-place)
        gemm_mfma<2><<<(NG + 63) / 64, 256, 0, stream>>>(
            M3, xg, nullptr, whi, wlo, l * 5 + 3, l * 5 + 4, 0, blr, nullptr, M3, NG, relu);
        xp = M1;
        xg = M3;
    }

    // ---- decoder ----
    scores_kernel<<<(E_lbl + 15) / 16, 256, 0, stream>>>(xp, xg, e_lbl, E_lbl, (float*)d_out);
}